// Round 10
// baseline (175.272 us; speedup 1.0000x reference)
//
#include <hip/hip_runtime.h>
#include <hip/hip_bf16.h>

#define N_NODES   4096
#define E_EDGES   262144
#define IN_DIM    256
#define EDGE_DIM  16
#define NAF       16
#define LATENT    128
#define NBT       5

#define LATENT_OFF 0
#define ATOMS_OFF  (N_NODES * LATENT)                 // 524288
#define BONDS_OFF  (ATOMS_OFF + N_NODES * NAF)        // 589824

// hash table: 2^20 u64 slots = 8 MB, load factor 0.25
#define TBITS 20
#define TSIZE (1u << TBITS)
#define TMASK (TSIZE - 1u)

typedef float    f32x4  __attribute__((ext_vector_type(4)));
typedef float    f32x4v __attribute__((ext_vector_type(4)));
typedef short    bf16x8 __attribute__((ext_vector_type(8)));
typedef unsigned u32x2  __attribute__((ext_vector_type(2)));
typedef unsigned u32x4  __attribute__((ext_vector_type(4)));

// silu via v_rcp_f32 (accuracy validated in R1: absmax unchanged)
__device__ __forceinline__ float silu_f(float x) {
    return x * __builtin_amdgcn_rcpf(1.0f + __expf(-x));
}

__device__ __forceinline__ unsigned pack_bf16x2(float lo, float hi) {
#if __has_builtin(__builtin_amdgcn_cvt_pk_bf16_f32)
    typedef __bf16 bf16x2_t __attribute__((ext_vector_type(2)));
    union { bf16x2_t v; unsigned u; } c;
    c.v = __builtin_amdgcn_cvt_pk_bf16_f32(lo, hi);
    return c.u;
#else
    union { float f; unsigned u; } a, b;
    a.f = lo; b.f = hi;
    const unsigned ra = (a.u + 0x7FFFu + ((a.u >> 16) & 1u)) >> 16;
    const unsigned rb = (b.u + 0x7FFFu + ((b.u >> 16) & 1u)) >> 16;
    return ra | (rb << 16);
#endif
}

__device__ __forceinline__ float bf_lo(unsigned u) {
    union { unsigned x; float f; } c; c.x = u << 16; return c.f;
}
__device__ __forceinline__ float bf_hi(unsigned u) {
    union { unsigned x; float f; } c; c.x = u & 0xFFFF0000u; return c.f;
}

// split fp32x8 into bf16 hi + bf16 lo fragments (x = hi + lo exactly to 2^-18)
__device__ __forceinline__ void split_bf16(const float4 x0, const float4 x1,
                                           bf16x8* hi, bf16x8* lo) {
    union { bf16x8 v; unsigned u[4]; } H, L;
    H.u[0] = pack_bf16x2(x0.x, x0.y);
    H.u[1] = pack_bf16x2(x0.z, x0.w);
    H.u[2] = pack_bf16x2(x1.x, x1.y);
    H.u[3] = pack_bf16x2(x1.z, x1.w);
    L.u[0] = pack_bf16x2(x0.x - bf_lo(H.u[0]), x0.y - bf_hi(H.u[0]));
    L.u[1] = pack_bf16x2(x0.z - bf_lo(H.u[1]), x0.w - bf_hi(H.u[1]));
    L.u[2] = pack_bf16x2(x1.x - bf_lo(H.u[2]), x1.y - bf_hi(H.u[2]));
    L.u[3] = pack_bf16x2(x1.z - bf_lo(H.u[3]), x1.w - bf_hi(H.u[3]));
    *hi = H.v; *lo = L.v;
}

// async gather: per-lane 16B global -> LDS[uniform base + lane*16]
__device__ __forceinline__ void gld_lds16(const void* g, void* l) {
    __builtin_amdgcn_global_load_lds(
        (const __attribute__((address_space(1))) unsigned*)g,
        (__attribute__((address_space(3))) unsigned*)l, 16, 0, 0);
}

__device__ __forceinline__ unsigned hashh(unsigned key) {
    return (key * 2654435761u) >> (32 - TBITS);
}

// 2-slot speculative resolve (R5, validated). Slow-path loads are dynamic but
// never counted in any vmcnt N -> only ever make counted waits stricter.
__device__ __forceinline__ int resolve2(const unsigned long long* __restrict__ tab,
                                        unsigned key, unsigned long long s0,
                                        unsigned long long s1, unsigned h) {
    if ((unsigned)(s0 >> 18) == key + 1u) return (int)(s0 & 0x3FFFFu);
    if (s0 == 0ULL) return -1;
    if ((unsigned)(s1 >> 18) == key + 1u) return (int)(s1 & 0x3FFFFu);
    if (s1 == 0ULL) return -1;
    h = (h + 2u) & TMASK;
    while (true) {
        const unsigned long long cur = tab[h];
        if (cur == 0ULL) return -1;
        if ((unsigned)(cur >> 18) == key + 1u) return (int)(cur & 0x3FFFFu);
        h = (h + 1u) & TMASK;
    }
}

// ---------------------------------------------------------------------------
// k_front: blocks 0..1023  : GEMM1
//          blocks 1024..2047: hash insert (direct-CAS, validated R6/R7)
//          block  2048      : prepack A1pre/A2pre
// ---------------------------------------------------------------------------
__global__ __launch_bounds__(256) void k_front(const float* __restrict__ s,
                                               const float* __restrict__ Wsh,
                                               const float* __restrict__ bsh,
                                               const int* __restrict__ eidx,
                                               const float* __restrict__ Wb,
                                               const float* __restrict__ bb,
                                               const float* __restrict__ Wbs,
                                               unsigned short* __restrict__ sact16,
                                               unsigned long long* __restrict__ tab,
                                               u32x4* __restrict__ A1pre,
                                               u32x4* __restrict__ A2pre) {
    const int blk = blockIdx.x;
    const int c   = threadIdx.x;

    if (blk >= 1024) {
        if (blk < 2048) {
            // ---- hash insert (winner = max edge id per key), direct CAS
            const int k = (blk - 1024) * 256 + c;
            const unsigned j = (unsigned)eidx[k];
            const unsigned i = (unsigned)eidx[E_EDGES + k];
            const unsigned key = (j << 12) | i;
            const unsigned long long mine =
                ((unsigned long long)(key + 1u) << 18) | (unsigned)k;
            unsigned h = hashh(key);
            while (true) {
                const unsigned long long old = atomicCAS(&tab[h], 0ULL, mine);
                if (old == 0ULL) return;                    // claimed empty slot
                if ((unsigned)(old >> 18) == key + 1u) {    // key already present
                    atomicMax(&tab[h], mine);
                    return;
                }
                h = (h + 1u) & TMASK;
            }
        } else {
            // ---- prepack: A1 = {Wb pair x2, pk(bb,0), 0}; A2 = {Wbs pair x2, 0, 0}
#pragma unroll
            for (int ee = 0; ee < 4; ++ee) {
                const int idx  = c + 256 * ee;
                const int g    = idx >> 6;
                const int lane = idx & 63;
                const int mm   = lane & 15;
                const int qq   = lane >> 4;

                const float4 w = *(const float4*)(Wb + (16 * g + mm) * EDGE_DIM + 4 * qq);
                u32x4 r1;
                r1.x = pack_bf16x2(w.x, w.y);
                r1.y = pack_bf16x2(w.z, w.w);
                r1.z = pack_bf16x2(bb[16 * g + mm], 0.0f);
                r1.w = 0u;
                A1pre[idx] = r1;

                u32x4 r2;
                if (mm < NBT) {
                    const float4 ws = *(const float4*)(Wbs + mm * IN_DIM + 16 * g + 4 * qq);
                    r2.x = pack_bf16x2(ws.x, ws.y);
                    r2.y = pack_bf16x2(ws.z, ws.w);
                } else {
                    r2.x = 0u; r2.y = 0u;
                }
                r2.z = 0u; r2.w = 0u;
                A2pre[idx] = r2;
            }
        }
        return;
    }

    // ---- GEMM1 tile: wave -> (row_tile, col_tile); 256 x 16 tiles
    const int lane = c & 63;
    const int wv   = c >> 6;
    const int wave = blk * 4 + wv;
    const int m    = lane & 15;
    const int q    = lane >> 4;
    const int row0 = (wave >> 4) * 16;
    const int col0 = (wave & 15) * 16;

    f32x4v acc;
    {
        const float bias = bsh[col0 + m];
        acc[0] = bias; acc[1] = bias; acc[2] = bias; acc[3] = bias;
    }

    const float* ap = s   + (size_t)(row0 + m) * IN_DIM + 8 * q;
    const float* bp = Wsh + (size_t)(col0 + m) * IN_DIM + 8 * q;

#pragma unroll
    for (int c8 = 0; c8 < 8; ++c8) {
        const float4 a0 = *(const float4*)(ap + 32 * c8);
        const float4 a1 = *(const float4*)(ap + 32 * c8 + 4);
        const float4 b0 = *(const float4*)(bp + 32 * c8);
        const float4 b1 = *(const float4*)(bp + 32 * c8 + 4);
        bf16x8 Ah, Al, Bh, Bl;
        split_bf16(a0, a1, &Ah, &Al);
        split_bf16(b0, b1, &Bh, &Bl);
        acc = __builtin_amdgcn_mfma_f32_16x16x32_bf16(Ah, Bh, acc, 0, 0, 0);
        acc = __builtin_amdgcn_mfma_f32_16x16x32_bf16(Al, Bh, acc, 0, 0, 0);
        acc = __builtin_amdgcn_mfma_f32_16x16x32_bf16(Ah, Bl, acc, 0, 0, 0);
    }

#pragma unroll
    for (int r = 0; r < 4; ++r) {
        const int row = row0 + 4 * q + r;
        const float v = silu_f(acc[r]);
        sact16[(size_t)row * IN_DIM + col0 + m] =
            (unsigned short)(pack_bf16x2(v, 0.0f) & 0xFFFFu);
    }
}

// fence helpers. Counted-wait safety rule (R3 post-mortem, R4/R5/R8/R9
// validated): vmcnt(N) targeting cluster X requires N <= #STATICALLY-issued
// loads younger than X not yet provably retired. Dynamic loads (hash slow
// path) and older stores are legal anywhere but NEVER counted -> FIFO
// retirement only makes waits stricter.
#define SB0()    __builtin_amdgcn_sched_barrier(0)
#define LGKM0()  do { __asm__ __volatile__("s_waitcnt lgkmcnt(0)" ::: "memory"); SB0(); } while (0)
#define VMW(n)   do { __asm__ __volatile__("s_waitcnt vmcnt(" #n ")" ::: "memory"); SB0(); } while (0)

// ---------------------------------------------------------------------------
// k_edges_mfma (R10): TA-transaction reduction.
//   blocks 0..1023   : PERSISTENT edge blocks, 4 waves x 4 tiles each.
//     A1/A2 MFMA fragment tables (32 KB of constants re-read by EVERY wave
//     from global in R9 = ~45% of all TA transactions) are loaded ONCE per
//     block into LDS; per-group reads become ds_read (LDS port, off TA path).
//   blocks 1024..1599: GEMM2 — atoms/latent = sact16@Wa^T + ba
// LDS: staging 4 x 6 KB (depth-3 eighths, R9 schedule) + tables 24 KB
//      = 48 KB/block -> 3 blocks/CU. TA-bound theory says occupancy loss
//      is fine (R8: +60% waves gave +3%).
// ---------------------------------------------------------------------------
__global__ __launch_bounds__(256, 3) void k_edges_mfma(const int* __restrict__ eidx,
                                                       const float* __restrict__ e,
                                                       const unsigned long long* __restrict__ tab,
                                                       const unsigned short* __restrict__ sact16,
                                                       const u32x4* __restrict__ A1pre,
                                                       const u32x4* __restrict__ A2pre,
                                                       const float* __restrict__ bbs,
                                                       const float* __restrict__ Wa,
                                                       const float* __restrict__ ba,
                                                       float* __restrict__ out) {
    __shared__ unsigned lds_all[4][1536];   // staging: 6 KB/wave
    __shared__ u32x4 ldsA1[1024];           // 16 KB: {Wb pair, Wb pair, pk(bb,0), 0}
    __shared__ u32x2 ldsA2[1024];           // 8 KB : {Wbs pair, Wbs pair}
    const int blk  = blockIdx.x;
    const int lane = threadIdx.x & 63;
    const int wv   = threadIdx.x >> 6;
    const int m    = lane & 15;
    const int q    = lane >> 4;

    if (blk >= 1024) {
        // ---- GEMM2: wave -> (row_tile, col_tile) over 256 x 9 tiles
        const int wave = (blk - 1024) * 4 + wv;   // 0..2303
        const int rt = wave / 9;
        const int ct = wave - rt * 9;
        const int row0  = rt * 16;
        const int n_abs = ct * 16 + m;            // 0..143

        f32x4v acc;
        {
            const float bias = ba[n_abs];
            acc[0] = bias; acc[1] = bias; acc[2] = bias; acc[3] = bias;
        }

        const unsigned short* apu = sact16 + (size_t)(row0 + m) * IN_DIM + 8 * q;
        const float*          bp  = Wa + (size_t)n_abs * IN_DIM + 8 * q;

#pragma unroll
        for (int c8 = 0; c8 < 8; ++c8) {
            const bf16x8 A = *(const bf16x8*)(apu + 32 * c8);
            const float4 b0 = *(const float4*)(bp + 32 * c8);
            const float4 b1 = *(const float4*)(bp + 32 * c8 + 4);
            bf16x8 Bh, Bl;
            split_bf16(b0, b1, &Bh, &Bl);
            acc = __builtin_amdgcn_mfma_f32_16x16x32_bf16(A, Bh, acc, 0, 0, 0);
            acc = __builtin_amdgcn_mfma_f32_16x16x32_bf16(A, Bl, acc, 0, 0, 0);
        }
#pragma unroll
        for (int r = 0; r < 4; ++r) {
            const int row = row0 + 4 * q + r;
            if (n_abs < NAF)
                out[ATOMS_OFF + (size_t)row * NAF + n_abs] = acc[r];
            else
                out[LATENT_OFF + (size_t)row * LATENT + (n_abs - NAF)] = acc[r];
        }
        return;
    }

    // ---- edge path: persistent block; cooperative table load (once)
    {
        const int tid = threadIdx.x;
#pragma unroll
        for (int t = 0; t < 4; ++t) {
            const int idx = tid + 256 * t;
            ldsA1[idx] = A1pre[idx];
            const u32x4 r2 = A2pre[idx];
            u32x2 p2; p2.x = r2.x; p2.y = r2.y;
            ldsA2[idx] = p2;
        }
    }
    __syncthreads();

    unsigned* myl = lds_all[wv];
    const short one_q0 = (q == 0) ? (short)0x3F80 : (short)0;  // bf16(1.0)

    f32x4v acc_init;
#pragma unroll
    for (int r = 0; r < 4; ++r) {
        const int bond = 4 * q + r;
        acc_init[r] = (bond < NBT) ? bbs[bond] : 0.0f;
    }
    const int qh = q >> 1;
    const int qw = 2 * (q & 1);
    const int mw = m * 4;
    const int wglob = blk * 4 + wv;

    for (int t = 0; t < 4; ++t) {
        const int k0 = __builtin_amdgcn_readfirstlane((wglob + 4096 * t) * 16);

        // -------- front: indices, probes --------
        const unsigned j_m = (unsigned)eidx[k0 + m];
        const unsigned i_m = (unsigned)eidx[E_EDGES + k0 + m];

        const char* si_base = (const char*)(sact16 + (size_t)i_m * IN_DIM);  // 512 B rows
        const char* sj_base = (const char*)(sact16 + (size_t)j_m * IN_DIM);

        const unsigned keyF = (j_m << 12) | i_m, keyR = (i_m << 12) | j_m;
        const unsigned hF = hashh(keyF), hR = hashh(keyR);
        const unsigned long long sF0 = tab[hF];
        const unsigned long long sF1 = tab[(hF + 1u) & TMASK];
        const unsigned long long sR0 = tab[hR];
        const unsigned long long sR1 = tab[(hR + 1u) & TMASK];

        // eighth staging (SB0-pinned, 2 static ops): eighth p = bytes
        // p*64..p*64+63 of each 512 B row; buf at byte qb: si @ qb, sj @ qb+1024.
        auto stage_e = [&](int p, int qb) {
            gld_lds16(si_base + p * 64 + q * 16, (char*)myl + qb);
            gld_lds16(sj_base + p * 64 + q * 16, (char*)myl + qb + 1024);
            SB0();
        };

        // prior tile's ds_reads must retire before overwriting staging bufs
        LGKM0();
        stage_e(0, 0);        // E0 -> buf0
        stage_e(1, 2048);     // E1 -> buf1
        stage_e(2, 4096);     // E2 -> buf2

        // -------- resolve (overlapped with staging flight) --------
        const int wf = resolve2(tab, keyF, sF0, sF1, hF);
        const int wr = resolve2(tab, keyR, sR0, sR1, hR);

        const float rsc = (wr >= 0) ? 0.5f : 0.0f;
        const int   wrc = (wr >= 0) ? wr : 0;
        const f32x4 ef = *(const f32x4*)(e + (size_t)wf  * EDGE_DIM + 4 * q);
        const f32x4 er = *(const f32x4*)(e + (size_t)wrc * EDGE_DIM + 4 * q);

        union { bf16x8 v; short s[8]; unsigned u[4]; } B1;
        {
            const f32x4 es = ef * 0.5f + er * rsc;
            B1.u[0] = pack_bf16x2(es[0], es[1]);
            B1.u[1] = pack_bf16x2(es[2], es[3]);
            B1.s[4] = one_q0; B1.s[5] = 0;
            B1.u[3] = 0u;
        }

        f32x4v acc0 = acc_init;
        f32x4v acc1 = {0.0f, 0.0f, 0.0f, 0.0f};

        // 2-group compute on one eighth-buffer at u32 offset qb4 (gbase = 2p):
        // group g reads off = (2*(g&1)+qh)*64 + m*4 + 2*(q&1); sj at +256 u32.
        // A1/A2 fragments from LDS tables (R10: off the TA path).
        auto qcompute2 = [&](int qb4, int gbase) {
#pragma unroll
            for (int gp = 0; gp < 2; ++gp) {
                const int g   = gbase + gp;
                const int off = (2 * gp + qh) * 64 + mw + qw;

                const u32x2 wi = *(const u32x2*)(myl + qb4 + off);
                const u32x2 wj = *(const u32x2*)(myl + qb4 + 256 + off);

                f32x4v C1;
                C1[0] = bf_lo(wi.x) + bf_lo(wj.x);
                C1[1] = bf_hi(wi.x) + bf_hi(wj.x);
                C1[2] = bf_lo(wi.y) + bf_lo(wj.y);
                C1[3] = bf_hi(wi.y) + bf_hi(wj.y);

                const u32x4 r1 = ldsA1[g * 64 + lane];
                const u32x2 r2 = ldsA2[g * 64 + lane];
                union { bf16x8 v; unsigned u[4]; } A1, A2;
                A1.u[0] = r1.x; A1.u[1] = r1.y; A1.u[2] = r1.z; A1.u[3] = 0u;
                A2.u[0] = r2.x; A2.u[1] = r2.y; A2.u[2] = 0u;   A2.u[3] = 0u;

                const f32x4v P = __builtin_amdgcn_mfma_f32_16x16x32_bf16(A1.v, B1.v, C1, 0, 0, 0);

                union { bf16x8 v; unsigned u[4]; } B2;
                B2.u[0] = pack_bf16x2(silu_f(P[0]), silu_f(P[1]));
                B2.u[1] = pack_bf16x2(silu_f(P[2]), silu_f(P[3]));
                B2.u[2] = 0u; B2.u[3] = 0u;

                if (gp & 1) acc1 = __builtin_amdgcn_mfma_f32_16x16x32_bf16(A2.v, B2.v, acc1, 0, 0, 0);
                else        acc0 = __builtin_amdgcn_mfma_f32_16x16x32_bf16(A2.v, B2.v, acc0, 0, 0, 0);
            }
        };

        // -------- 8-phase depth-3 counted-vmcnt pipeline (R9 schedule) --------
        // B1's compiler wait on ef/er (youngest loads) drains E0-E2 (FIFO);
        // explicit VMW(0) is the async-LDS fence (rule 21), timing-free here.
        // Prior tile's bond stores are OLDER than all clusters -> stricter only.
        VMW(0);
        qcompute2(0, 0);        // E0 @ buf0
        LGKM0(); stage_e(3, 0);        // E3 -> buf0

        VMW(2);                 // free: E1 already drained; <= {E3} outstanding
        qcompute2(512, 2);      // E1 @ buf1
        LGKM0(); stage_e(4, 2048);     // E4 -> buf1

        VMW(4);                 // free: E2 drained; <= {E3,E4} outstanding
        qcompute2(1024, 4);     // E2 @ buf2
        LGKM0(); stage_e(5, 4096);     // E5 -> buf2

        VMW(4);                 // E3 done (younger static: E4,E5 = 4)
        qcompute2(0, 6);        // E3 @ buf0
        LGKM0(); stage_e(6, 0);        // E6 -> buf0

        VMW(4);                 // E4 done (younger static: E5,E6 = 4)
        qcompute2(512, 8);      // E4 @ buf1
        LGKM0(); stage_e(7, 2048);     // E7 -> buf1

        VMW(4);                 // E5 done (younger static: E6,E7 = 4)
        qcompute2(1024, 10);    // E5 @ buf2

        VMW(2);                 // E6 done (younger static: E7 = 2)
        qcompute2(0, 12);       // E6 @ buf0

        VMW(0);                 // E7 done
        qcompute2(512, 14);     // E7 @ buf1

        // -------- store bonds (plain stores; R9: WRITE_SIZE 7.5 MB) --------
        const f32x4v accT = acc0 + acc1;
        float* op = out + BONDS_OFF + (size_t)(k0 + m) * NBT;
        if (q == 0) {
            op[0] = accT[0];
            op[1] = accT[1];
            op[2] = accT[2];
            op[3] = accT[3];
        } else if (q == 1) {
            op[4] = accT[0];
        }
    }
}

// ---------------------------------------------------------------------------
extern "C" void kernel_launch(void* const* d_in, const int* in_sizes, int n_in,
                              void* d_out, int out_size, void* d_ws, size_t ws_size,
                              hipStream_t stream) {
    const float* s   = (const float*)d_in[0];
    const float* e   = (const float*)d_in[1];
    const int*   eix = (const int*)d_in[3];
    const float* Wsh = (const float*)d_in[4];
    const float* bsh = (const float*)d_in[5];
    const float* Wb  = (const float*)d_in[6];
    const float* bbo = (const float*)d_in[7];
    const float* Wbs = (const float*)d_in[8];
    const float* bbs = (const float*)d_in[9];
    const float* Wa  = (const float*)d_in[10];
    const float* ba  = (const float*)d_in[11];
    float* out = (float*)d_out;

    char* ws = (char*)d_ws;
    unsigned short*     sact16 = (unsigned short*)ws;             // 2 MB @ 0
    u32x4*              A1pre  = (u32x4*)(ws + (2u << 20));       // 16 KB
    u32x4*              A2pre  = (u32x4*)(ws + (2u << 20) + 16384);
    unsigned long long* tab    = (unsigned long long*)(ws + (3u << 20)); // 8 MB

    (void)hipMemsetAsync(tab, 0x00, TSIZE * sizeof(unsigned long long), stream);

    k_front<<<2049, 256, 0, stream>>>(s, Wsh, bsh, eix, Wb, bbo, Wbs,
                                      sact16, tab, A1pre, A2pre);
    k_edges_mfma<<<1600, 256, 0, stream>>>(eix, e, tab, sact16,
                                           A1pre, A2pre, bbs, Wa, ba, out);
}

// Round 11
// 172.256 us; speedup vs baseline: 1.0175x; 1.0175x over previous
//
#include <hip/hip_runtime.h>
#include <hip/hip_bf16.h>

#define N_NODES   4096
#define E_EDGES   262144
#define IN_DIM    256
#define EDGE_DIM  16
#define NAF       16
#define LATENT    128
#define NBT       5

#define LATENT_OFF 0
#define ATOMS_OFF  (N_NODES * LATENT)                 // 524288
#define BONDS_OFF  (ATOMS_OFF + N_NODES * NAF)        // 589824

// hash table: 2^20 u64 slots = 8 MB, load factor 0.25
#define TBITS 20
#define TSIZE (1u << TBITS)
#define TMASK (TSIZE - 1u)

typedef float    f32x4  __attribute__((ext_vector_type(4)));
typedef float    f32x4v __attribute__((ext_vector_type(4)));
typedef short    bf16x8 __attribute__((ext_vector_type(8)));
typedef unsigned u32x2  __attribute__((ext_vector_type(2)));
typedef unsigned u32x4  __attribute__((ext_vector_type(4)));

// silu via v_rcp_f32 (accuracy validated in R1: absmax unchanged)
__device__ __forceinline__ float silu_f(float x) {
    return x * __builtin_amdgcn_rcpf(1.0f + __expf(-x));
}

__device__ __forceinline__ unsigned pack_bf16x2(float lo, float hi) {
#if __has_builtin(__builtin_amdgcn_cvt_pk_bf16_f32)
    typedef __bf16 bf16x2_t __attribute__((ext_vector_type(2)));
    union { bf16x2_t v; unsigned u; } c;
    c.v = __builtin_amdgcn_cvt_pk_bf16_f32(lo, hi);
    return c.u;
#else
    union { float f; unsigned u; } a, b;
    a.f = lo; b.f = hi;
    const unsigned ra = (a.u + 0x7FFFu + ((a.u >> 16) & 1u)) >> 16;
    const unsigned rb = (b.u + 0x7FFFu + ((b.u >> 16) & 1u)) >> 16;
    return ra | (rb << 16);
#endif
}

__device__ __forceinline__ float bf_lo(unsigned u) {
    union { unsigned x; float f; } c; c.x = u << 16; return c.f;
}
__device__ __forceinline__ float bf_hi(unsigned u) {
    union { unsigned x; float f; } c; c.x = u & 0xFFFF0000u; return c.f;
}

// split fp32x8 into bf16 hi + bf16 lo fragments (x = hi + lo exactly to 2^-18)
__device__ __forceinline__ void split_bf16(const float4 x0, const float4 x1,
                                           bf16x8* hi, bf16x8* lo) {
    union { bf16x8 v; unsigned u[4]; } H, L;
    H.u[0] = pack_bf16x2(x0.x, x0.y);
    H.u[1] = pack_bf16x2(x0.z, x0.w);
    H.u[2] = pack_bf16x2(x1.x, x1.y);
    H.u[3] = pack_bf16x2(x1.z, x1.w);
    L.u[0] = pack_bf16x2(x0.x - bf_lo(H.u[0]), x0.y - bf_hi(H.u[0]));
    L.u[1] = pack_bf16x2(x0.z - bf_lo(H.u[1]), x0.w - bf_hi(H.u[1]));
    L.u[2] = pack_bf16x2(x1.x - bf_lo(H.u[2]), x1.y - bf_hi(H.u[2]));
    L.u[3] = pack_bf16x2(x1.z - bf_lo(H.u[3]), x1.w - bf_hi(H.u[3]));
    *hi = H.v; *lo = L.v;
}

// async gather: per-lane 16B global -> LDS[uniform base + lane*16]
__device__ __forceinline__ void gld_lds16(const void* g, void* l) {
    __builtin_amdgcn_global_load_lds(
        (const __attribute__((address_space(1))) unsigned*)g,
        (__attribute__((address_space(3))) unsigned*)l, 16, 0, 0);
}

__device__ __forceinline__ unsigned hashh(unsigned key) {
    return (key * 2654435761u) >> (32 - TBITS);
}

// 2-slot speculative resolve (R5, validated). Slow-path loads are dynamic but
// never counted in any vmcnt N -> only ever make counted waits stricter.
__device__ __forceinline__ int resolve2(const unsigned long long* __restrict__ tab,
                                        unsigned key, unsigned long long s0,
                                        unsigned long long s1, unsigned h) {
    if ((unsigned)(s0 >> 18) == key + 1u) return (int)(s0 & 0x3FFFFu);
    if (s0 == 0ULL) return -1;
    if ((unsigned)(s1 >> 18) == key + 1u) return (int)(s1 & 0x3FFFFu);
    if (s1 == 0ULL) return -1;
    h = (h + 2u) & TMASK;
    while (true) {
        const unsigned long long cur = tab[h];
        if (cur == 0ULL) return -1;
        if ((unsigned)(cur >> 18) == key + 1u) return (int)(cur & 0x3FFFFu);
        h = (h + 1u) & TMASK;
    }
}

// ---------------------------------------------------------------------------
// k_front (R11): blocks 0..511   : GEMM1, block-cooperative.
//   Block = 64 rows x 32 cols. Wsh col-panel (32 rows x 256) pre-SPLIT into
//   LDS bf16 hi/lo once per block (33.8 KB), shared by 4 waves; each wave =
//   16 rows x 2 col-tiles with A-split amortized. Streamed traffic: 128 MB
//   (R9 form: s x16 + Wsh x16 re-reads) -> 48 MB (s x8 + Wsh panel x1/blk).
//   FP path identical to R9 (same splits, same 3-MFMA order) -> same output.
//          blocks 512..1535: hash insert (direct-CAS, validated R6/R7)
//          block  1536     : prepack A1pre/A2pre
// ---------------------------------------------------------------------------
__global__ __launch_bounds__(256) void k_front(const float* __restrict__ s,
                                               const float* __restrict__ Wsh,
                                               const float* __restrict__ bsh,
                                               const int* __restrict__ eidx,
                                               const float* __restrict__ Wb,
                                               const float* __restrict__ bb,
                                               const float* __restrict__ Wbs,
                                               unsigned short* __restrict__ sact16,
                                               unsigned long long* __restrict__ tab,
                                               u32x4* __restrict__ A1pre,
                                               u32x4* __restrict__ A2pre) {
    // Wsh panel, pre-split: rows = output cols cg*32..+31, padded to 264
    // shorts/row (528 B: 16B-aligned, stride 132 words -> worst ~2-4-way
    // conflict, acceptable). 2 x 16.9 KB = 33.8 KB.
    __shared__ short sWh[32][264];
    __shared__ short sWl[32][264];

    const int blk = blockIdx.x;
    const int c   = threadIdx.x;

    if (blk >= 512) {
        if (blk < 1536) {
            // ---- hash insert (winner = max edge id per key), direct CAS
            const int k = (blk - 512) * 256 + c;
            const unsigned j = (unsigned)eidx[k];
            const unsigned i = (unsigned)eidx[E_EDGES + k];
            const unsigned key = (j << 12) | i;
            const unsigned long long mine =
                ((unsigned long long)(key + 1u) << 18) | (unsigned)k;
            unsigned h = hashh(key);
            while (true) {
                const unsigned long long old = atomicCAS(&tab[h], 0ULL, mine);
                if (old == 0ULL) return;                    // claimed empty slot
                if ((unsigned)(old >> 18) == key + 1u) {    // key already present
                    atomicMax(&tab[h], mine);
                    return;
                }
                h = (h + 1u) & TMASK;
            }
        } else {
            // ---- prepack: A1 = {Wb pair x2, pk(bb,0), 0}; A2 = {Wbs pair x2, 0, 0}
#pragma unroll
            for (int ee = 0; ee < 4; ++ee) {
                const int idx  = c + 256 * ee;
                const int g    = idx >> 6;
                const int lane = idx & 63;
                const int mm   = lane & 15;
                const int qq   = lane >> 4;

                const float4 w = *(const float4*)(Wb + (16 * g + mm) * EDGE_DIM + 4 * qq);
                u32x4 r1;
                r1.x = pack_bf16x2(w.x, w.y);
                r1.y = pack_bf16x2(w.z, w.w);
                r1.z = pack_bf16x2(bb[16 * g + mm], 0.0f);
                r1.w = 0u;
                A1pre[idx] = r1;

                u32x4 r2;
                if (mm < NBT) {
                    const float4 ws = *(const float4*)(Wbs + mm * IN_DIM + 16 * g + 4 * qq);
                    r2.x = pack_bf16x2(ws.x, ws.y);
                    r2.y = pack_bf16x2(ws.z, ws.w);
                } else {
                    r2.x = 0u; r2.y = 0u;
                }
                r2.z = 0u; r2.w = 0u;
                A2pre[idx] = r2;
            }
        }
        return;
    }

    // ---- GEMM1: block (rg, cg) = rows rg*64..+63, cols cg*32..+31
    const int rg = blk >> 3;        // 0..63
    const int cg = blk & 7;         // 0..7

    // cooperative fill: thread -> row c>>3 (0..31), chunk-of-8 ch = (c&7)+8k
    {
        const int r  = c >> 3;
        const int cq = c & 7;
        const float* wrow = Wsh + (size_t)(cg * 32 + r) * IN_DIM;
#pragma unroll
        for (int k = 0; k < 4; ++k) {
            const int ch = cq + 8 * k;                    // 0..31
            const float4 b0 = *(const float4*)(wrow + ch * 8);
            const float4 b1 = *(const float4*)(wrow + ch * 8 + 4);
            bf16x8 Bh, Bl;
            split_bf16(b0, b1, &Bh, &Bl);
            *(bf16x8*)&sWh[r][ch * 8] = Bh;
            *(bf16x8*)&sWl[r][ch * 8] = Bl;
        }
    }
    __syncthreads();

    const int lane = c & 63;
    const int wv   = c >> 6;
    const int m    = lane & 15;
    const int q    = lane >> 4;
    const int row0 = rg * 64 + wv * 16;

    f32x4v acc0, acc1;
    {
        const float b0 = bsh[cg * 32 + m];
        const float b1 = bsh[cg * 32 + 16 + m];
        acc0[0] = b0; acc0[1] = b0; acc0[2] = b0; acc0[3] = b0;
        acc1[0] = b1; acc1[1] = b1; acc1[2] = b1; acc1[3] = b1;
    }

    const float* ap = s + (size_t)(row0 + m) * IN_DIM + 8 * q;

#pragma unroll
    for (int c8 = 0; c8 < 8; ++c8) {
        const float4 a0 = *(const float4*)(ap + 32 * c8);
        const float4 a1 = *(const float4*)(ap + 32 * c8 + 4);
        bf16x8 Ah, Al;
        split_bf16(a0, a1, &Ah, &Al);

        // col-tile 0 (cols cg*32 + m)
        {
            const bf16x8 Bh = *(const bf16x8*)&sWh[m][32 * c8 + 8 * q];
            const bf16x8 Bl = *(const bf16x8*)&sWl[m][32 * c8 + 8 * q];
            acc0 = __builtin_amdgcn_mfma_f32_16x16x32_bf16(Ah, Bh, acc0, 0, 0, 0);
            acc0 = __builtin_amdgcn_mfma_f32_16x16x32_bf16(Al, Bh, acc0, 0, 0, 0);
            acc0 = __builtin_amdgcn_mfma_f32_16x16x32_bf16(Ah, Bl, acc0, 0, 0, 0);
        }
        // col-tile 1 (cols cg*32 + 16 + m)
        {
            const bf16x8 Bh = *(const bf16x8*)&sWh[16 + m][32 * c8 + 8 * q];
            const bf16x8 Bl = *(const bf16x8*)&sWl[16 + m][32 * c8 + 8 * q];
            acc1 = __builtin_amdgcn_mfma_f32_16x16x32_bf16(Ah, Bh, acc1, 0, 0, 0);
            acc1 = __builtin_amdgcn_mfma_f32_16x16x32_bf16(Al, Bh, acc1, 0, 0, 0);
            acc1 = __builtin_amdgcn_mfma_f32_16x16x32_bf16(Ah, Bl, acc1, 0, 0, 0);
        }
    }

    // D: rows row0+4q+r; cols cg*32 + {m, 16+m}
#pragma unroll
    for (int r = 0; r < 4; ++r) {
        const int row = row0 + 4 * q + r;
        const float v0 = silu_f(acc0[r]);
        const float v1 = silu_f(acc1[r]);
        sact16[(size_t)row * IN_DIM + cg * 32 + m] =
            (unsigned short)(pack_bf16x2(v0, 0.0f) & 0xFFFFu);
        sact16[(size_t)row * IN_DIM + cg * 32 + 16 + m] =
            (unsigned short)(pack_bf16x2(v1, 0.0f) & 0xFFFFu);
    }
}

// fence helpers. Counted-wait safety rule (R3 post-mortem, R4/R5/R8/R9
// validated): vmcnt(N) targeting cluster X requires N <= #STATICALLY-issued
// loads younger than X not yet provably retired. Dynamic loads (hash slow
// path) and older stores are legal anywhere but NEVER counted -> FIFO
// retirement only makes waits stricter.
#define SB0()    __builtin_amdgcn_sched_barrier(0)
#define LGKM0()  do { __asm__ __volatile__("s_waitcnt lgkmcnt(0)" ::: "memory"); SB0(); } while (0)
#define VMW(n)   do { __asm__ __volatile__("s_waitcnt vmcnt(" #n ")" ::: "memory"); SB0(); } while (0)

// ---------------------------------------------------------------------------
// k_edges_mfma (R9 verbatim — best verified: 69.5 µs):
//   blocks 0..4095  : edge tiles, 1 tile/wave, eighth-staged TRIPLE buffer
//   blocks 4096..4671: GEMM2 — atoms/latent = sact16@Wa^T + ba
// ---------------------------------------------------------------------------
__global__ __launch_bounds__(256, 6) void k_edges_mfma(const int* __restrict__ eidx,
                                                       const float* __restrict__ e,
                                                       const unsigned long long* __restrict__ tab,
                                                       const unsigned short* __restrict__ sact16,
                                                       const u32x4* __restrict__ A1pre,
                                                       const u32x4* __restrict__ A2pre,
                                                       const float* __restrict__ bbs,
                                                       const float* __restrict__ Wa,
                                                       const float* __restrict__ ba,
                                                       float* __restrict__ out) {
    __shared__ unsigned lds_all[4][1536];   // 6 KB/wave -> 24 KB/block
    const int blk  = blockIdx.x;
    const int lane = threadIdx.x & 63;
    const int wv   = threadIdx.x >> 6;
    const int m    = lane & 15;
    const int q    = lane >> 4;

    if (blk >= 4096) {
        // ---- GEMM2: wave -> (row_tile, col_tile) over 256 x 9 tiles
        const int wave = (blk - 4096) * 4 + wv;   // 0..2303
        const int rt = wave / 9;
        const int ct = wave - rt * 9;
        const int row0  = rt * 16;
        const int n_abs = ct * 16 + m;            // 0..143

        f32x4v acc;
        {
            const float bias = ba[n_abs];
            acc[0] = bias; acc[1] = bias; acc[2] = bias; acc[3] = bias;
        }

        const unsigned short* apu = sact16 + (size_t)(row0 + m) * IN_DIM + 8 * q;
        const float*          bp  = Wa + (size_t)n_abs * IN_DIM + 8 * q;

#pragma unroll
        for (int c8 = 0; c8 < 8; ++c8) {
            const bf16x8 A = *(const bf16x8*)(apu + 32 * c8);
            const float4 b0 = *(const float4*)(bp + 32 * c8);
            const float4 b1 = *(const float4*)(bp + 32 * c8 + 4);
            bf16x8 Bh, Bl;
            split_bf16(b0, b1, &Bh, &Bl);
            acc = __builtin_amdgcn_mfma_f32_16x16x32_bf16(A, Bh, acc, 0, 0, 0);
            acc = __builtin_amdgcn_mfma_f32_16x16x32_bf16(A, Bl, acc, 0, 0, 0);
        }
#pragma unroll
        for (int r = 0; r < 4; ++r) {
            const int row = row0 + 4 * q + r;
            if (n_abs < NAF)
                out[ATOMS_OFF + (size_t)row * NAF + n_abs] = acc[r];
            else
                out[LATENT_OFF + (size_t)row * LATENT + (n_abs - NAF)] = acc[r];
        }
        return;
    }

    // ---- edge tile: 1 tile (16 edges) per wave
    const int k0 = __builtin_amdgcn_readfirstlane((blk * 4 + wv) * 16);
    unsigned* myl = lds_all[wv];
    const short one_q0 = (q == 0) ? (short)0x3F80 : (short)0;  // bf16(1.0)

    f32x4v acc_init;
#pragma unroll
    for (int r = 0; r < 4; ++r) {
        const int bond = 4 * q + r;
        acc_init[r] = (bond < NBT) ? bbs[bond] : 0.0f;
    }
    const int qh = q >> 1;
    const int qw = 2 * (q & 1);
    const int mw = m * 4;

    // -------- issue phase --------
    const unsigned j_m = (unsigned)eidx[k0 + m];
    const unsigned i_m = (unsigned)eidx[E_EDGES + k0 + m];

    const char* si_base = (const char*)(sact16 + (size_t)i_m * IN_DIM);  // 512 B rows
    const char* sj_base = (const char*)(sact16 + (size_t)j_m * IN_DIM);

    const unsigned keyF = (j_m << 12) | i_m, keyR = (i_m << 12) | j_m;
    const unsigned hF = hashh(keyF), hR = hashh(keyR);
    const unsigned long long sF0 = tab[hF];
    const unsigned long long sF1 = tab[(hF + 1u) & TMASK];
    const unsigned long long sR0 = tab[hR];
    const unsigned long long sR1 = tab[(hR + 1u) & TMASK];

    // eighth staging (SB0-pinned, 2 static ops): eighth p = bytes p*64..p*64+63
    // of each 512 B row. Buffer at byte qb: si 1 KB @ qb, sj 1 KB @ qb+1024.
    auto stage_e = [&](int p, int qb) {
        gld_lds16(si_base + p * 64 + q * 16, (char*)myl + qb);
        gld_lds16(sj_base + p * 64 + q * 16, (char*)myl + qb + 1024);
        SB0();
    };

    stage_e(0, 0);        // E0 -> buf0
    stage_e(1, 2048);     // E1 -> buf1
    stage_e(2, 4096);     // E2 -> buf2

    // -------- resolve (overlapped with staging flight) --------
    const int wf = resolve2(tab, keyF, sF0, sF1, hF);
    const int wr = resolve2(tab, keyR, sR0, sR1, hR);

    const float rsc = (wr >= 0) ? 0.5f : 0.0f;
    const int   wrc = (wr >= 0) ? wr : 0;
    const f32x4 ef = *(const f32x4*)(e + (size_t)wf  * EDGE_DIM + 4 * q);
    const f32x4 er = *(const f32x4*)(e + (size_t)wrc * EDGE_DIM + 4 * q);

    union { bf16x8 v; short s[8]; unsigned u[4]; } B1;
    {
        const f32x4 es = ef * 0.5f + er * rsc;
        B1.u[0] = pack_bf16x2(es[0], es[1]);
        B1.u[1] = pack_bf16x2(es[2], es[3]);
        B1.s[4] = one_q0; B1.s[5] = 0;
        B1.u[3] = 0u;
    }

    f32x4v acc0 = acc_init;
    f32x4v acc1 = {0.0f, 0.0f, 0.0f, 0.0f};

    // 2-group compute on one eighth-buffer at u32 offset qb4 (gbase = 2p):
    // group g reads off = (2*(g&1)+qh)*64 + m*4 + 2*(q&1); sj at +256 u32.
    auto qcompute2 = [&](int qb4, int gbase) {
#pragma unroll
        for (int gp = 0; gp < 2; ++gp) {
            const int g   = gbase + gp;
            const int off = (2 * gp + qh) * 64 + mw + qw;

            const u32x2 wi = *(const u32x2*)(myl + qb4 + off);
            const u32x2 wj = *(const u32x2*)(myl + qb4 + 256 + off);

            f32x4v C1;
            C1[0] = bf_lo(wi.x) + bf_lo(wj.x);
            C1[1] = bf_hi(wi.x) + bf_hi(wj.x);
            C1[2] = bf_lo(wi.y) + bf_lo(wj.y);
            C1[3] = bf_hi(wi.y) + bf_hi(wj.y);

            const u32x4 r1 = A1pre[g * 64 + lane];
            const u32x4 r2 = A2pre[g * 64 + lane];
            union { bf16x8 v; unsigned u[4]; } A1, A2;
            A1.u[0] = r1.x; A1.u[1] = r1.y; A1.u[2] = r1.z; A1.u[3] = 0u;
            A2.u[0] = r2.x; A2.u[1] = r2.y; A2.u[2] = 0u;   A2.u[3] = 0u;

            const f32x4v P = __builtin_amdgcn_mfma_f32_16x16x32_bf16(A1.v, B1.v, C1, 0, 0, 0);

            union { bf16x8 v; unsigned u[4]; } B2;
            B2.u[0] = pack_bf16x2(silu_f(P[0]), silu_f(P[1]));
            B2.u[1] = pack_bf16x2(silu_f(P[2]), silu_f(P[3]));
            B2.u[2] = 0u; B2.u[3] = 0u;

            if (gp & 1) acc1 = __builtin_amdgcn_mfma_f32_16x16x32_bf16(A2.v, B2.v, acc1, 0, 0, 0);
            else        acc0 = __builtin_amdgcn_mfma_f32_16x16x32_bf16(A2.v, B2.v, acc0, 0, 0, 0);
        }
    };

    // -------- 8-phase depth-3 counted-vmcnt pipeline --------
    // B1's compiler wait on ef/er (youngest loads) drains E0-E2 (FIFO);
    // explicit VMW(0) is the async-LDS fence (rule 21), timing-free here.
    VMW(0);
    qcompute2(0, 0);        // E0 @ buf0
    LGKM0(); stage_e(3, 0);        // E3 -> buf0

    VMW(2);                 // free: E1 already drained; <= {E3} outstanding
    qcompute2(512, 2);      // E1 @ buf1
    LGKM0(); stage_e(4, 2048);     // E4 -> buf1

    VMW(4);                 // free: E2 drained; <= {E3,E4} outstanding
    qcompute2(1024, 4);     // E2 @ buf2
    LGKM0(); stage_e(5, 4096);     // E5 -> buf2

    VMW(4);                 // E3 done (younger static: E4,E5 = 4)
    qcompute2(0, 6);        // E3 @ buf0
    LGKM0(); stage_e(6, 0);        // E6 -> buf0

    VMW(4);                 // E4 done (younger static: E5,E6 = 4)
    qcompute2(512, 8);      // E4 @ buf1
    LGKM0(); stage_e(7, 2048);     // E7 -> buf1

    VMW(4);                 // E5 done (younger static: E6,E7 = 4)
    qcompute2(1024, 10);    // E5 @ buf2

    VMW(2);                 // E6 done (younger static: E7 = 2)
    qcompute2(0, 12);       // E6 @ buf0

    VMW(0);                 // E7 done
    qcompute2(512, 14);     // E7 @ buf1

    // -------- store bonds (plain stores; WRITE_SIZE 7.5 MB in R9) --------
    const f32x4v accT = acc0 + acc1;
    float* op = out + BONDS_OFF + (size_t)(k0 + m) * NBT;
    if (q == 0) {
        op[0] = accT[0];
        op[1] = accT[1];
        op[2] = accT[2];
        op[3] = accT[3];
    } else if (q == 1) {
        op[4] = accT[0];
    }
}

// ---------------------------------------------------------------------------
extern "C" void kernel_launch(void* const* d_in, const int* in_sizes, int n_in,
                              void* d_out, int out_size, void* d_ws, size_t ws_size,
                              hipStream_t stream) {
    const float* s   = (const float*)d_in[0];
    const float* e   = (const float*)d_in[1];
    const int*   eix = (const int*)d_in[3];
    const float* Wsh = (const float*)d_in[4];
    const float* bsh = (const float*)d_in[5];
    const float* Wb  = (const float*)d_in[6];
    const float* bbo = (const float*)d_in[7];
    const float* Wbs = (const float*)d_in[8];
    const float* bbs = (const float*)d_in[9];
    const float* Wa  = (const float*)d_in[10];
    const float* ba  = (const float*)d_in[11];
    float* out = (float*)d_out;

    char* ws = (char*)d_ws;
    unsigned short*     sact16 = (unsigned short*)ws;             // 2 MB @ 0
    u32x4*              A1pre  = (u32x4*)(ws + (2u << 20));       // 16 KB
    u32x4*              A2pre  = (u32x4*)(ws + (2u << 20) + 16384);
    unsigned long long* tab    = (unsigned long long*)(ws + (3u << 20)); // 8 MB

    (void)hipMemsetAsync(tab, 0x00, TSIZE * sizeof(unsigned long long), stream);

    k_front<<<1537, 256, 0, stream>>>(s, Wsh, bsh, eix, Wb, bbo, Wbs,
                                      sact16, tab, A1pre, A2pre);
    k_edges_mfma<<<4672, 256, 0, stream>>>(eix, e, tab, sact16,
                                           A1pre, A2pre, bbs, Wa, ba, out);
}

// Round 12
// 169.774 us; speedup vs baseline: 1.0324x; 1.0146x over previous
//
#include <hip/hip_runtime.h>
#include <hip/hip_bf16.h>

#define N_NODES   4096
#define E_EDGES   262144
#define IN_DIM    256
#define EDGE_DIM  16
#define NAF       16
#define LATENT    128
#define NBT       5

#define LATENT_OFF 0
#define ATOMS_OFF  (N_NODES * LATENT)                 // 524288
#define BONDS_OFF  (ATOMS_OFF + N_NODES * NAF)        // 589824

// hash table: 2^20 u64 slots = 8 MB, load factor 0.25
#define TBITS 20
#define TSIZE (1u << TBITS)
#define TMASK (TSIZE - 1u)

typedef float    f32x4  __attribute__((ext_vector_type(4)));
typedef float    f32x4v __attribute__((ext_vector_type(4)));
typedef short    bf16x8 __attribute__((ext_vector_type(8)));
typedef unsigned u32x2  __attribute__((ext_vector_type(2)));
typedef unsigned u32x4  __attribute__((ext_vector_type(4)));

// silu via v_rcp_f32 (accuracy validated in R1: absmax unchanged)
__device__ __forceinline__ float silu_f(float x) {
    return x * __builtin_amdgcn_rcpf(1.0f + __expf(-x));
}

__device__ __forceinline__ unsigned pack_bf16x2(float lo, float hi) {
#if __has_builtin(__builtin_amdgcn_cvt_pk_bf16_f32)
    typedef __bf16 bf16x2_t __attribute__((ext_vector_type(2)));
    union { bf16x2_t v; unsigned u; } c;
    c.v = __builtin_amdgcn_cvt_pk_bf16_f32(lo, hi);
    return c.u;
#else
    union { float f; unsigned u; } a, b;
    a.f = lo; b.f = hi;
    const unsigned ra = (a.u + 0x7FFFu + ((a.u >> 16) & 1u)) >> 16;
    const unsigned rb = (b.u + 0x7FFFu + ((b.u >> 16) & 1u)) >> 16;
    return ra | (rb << 16);
#endif
}

__device__ __forceinline__ float bf_lo(unsigned u) {
    union { unsigned x; float f; } c; c.x = u << 16; return c.f;
}
__device__ __forceinline__ float bf_hi(unsigned u) {
    union { unsigned x; float f; } c; c.x = u & 0xFFFF0000u; return c.f;
}

// split fp32x8 into bf16 hi + bf16 lo fragments (x = hi + lo exactly to 2^-18)
__device__ __forceinline__ void split_bf16(const float4 x0, const float4 x1,
                                           bf16x8* hi, bf16x8* lo) {
    union { bf16x8 v; unsigned u[4]; } H, L;
    H.u[0] = pack_bf16x2(x0.x, x0.y);
    H.u[1] = pack_bf16x2(x0.z, x0.w);
    H.u[2] = pack_bf16x2(x1.x, x1.y);
    H.u[3] = pack_bf16x2(x1.z, x1.w);
    L.u[0] = pack_bf16x2(x0.x - bf_lo(H.u[0]), x0.y - bf_hi(H.u[0]));
    L.u[1] = pack_bf16x2(x0.z - bf_lo(H.u[1]), x0.w - bf_hi(H.u[1]));
    L.u[2] = pack_bf16x2(x1.x - bf_lo(H.u[2]), x1.y - bf_hi(H.u[2]));
    L.u[3] = pack_bf16x2(x1.z - bf_lo(H.u[3]), x1.w - bf_hi(H.u[3]));
    *hi = H.v; *lo = L.v;
}

// async gather: per-lane 16B global -> LDS[uniform base + lane*16]
__device__ __forceinline__ void gld_lds16(const void* g, void* l) {
    __builtin_amdgcn_global_load_lds(
        (const __attribute__((address_space(1))) unsigned*)g,
        (__attribute__((address_space(3))) unsigned*)l, 16, 0, 0);
}

__device__ __forceinline__ unsigned hashh(unsigned key) {
    return (key * 2654435761u) >> (32 - TBITS);
}

// 2-slot speculative resolve (R5, validated). Slow-path loads are dynamic but
// never counted in any vmcnt N -> only ever make counted waits stricter.
__device__ __forceinline__ int resolve2(const unsigned long long* __restrict__ tab,
                                        unsigned key, unsigned long long s0,
                                        unsigned long long s1, unsigned h) {
    if ((unsigned)(s0 >> 18) == key + 1u) return (int)(s0 & 0x3FFFFu);
    if (s0 == 0ULL) return -1;
    if ((unsigned)(s1 >> 18) == key + 1u) return (int)(s1 & 0x3FFFFu);
    if (s1 == 0ULL) return -1;
    h = (h + 2u) & TMASK;
    while (true) {
        const unsigned long long cur = tab[h];
        if (cur == 0ULL) return -1;
        if ((unsigned)(cur >> 18) == key + 1u) return (int)(cur & 0x3FFFFu);
        h = (h + 1u) & TMASK;
    }
}

// ---------------------------------------------------------------------------
// k_front (R11 structure + R12 slotk memo):
//   blocks 0..511   : GEMM1, block-cooperative (R11, validated: -4 us)
//   blocks 512..1535: hash insert (direct-CAS); NEW: records slotk[k] = the
//                     unique resting slot of edge k's key -> edge kernel does
//                     a DIRECT tab[slotk[k]] load (no forward probing).
//   block  1536     : prepack A1pre/A2pre
// ---------------------------------------------------------------------------
__global__ __launch_bounds__(256) void k_front(const float* __restrict__ s,
                                               const float* __restrict__ Wsh,
                                               const float* __restrict__ bsh,
                                               const int* __restrict__ eidx,
                                               const float* __restrict__ Wb,
                                               const float* __restrict__ bb,
                                               const float* __restrict__ Wbs,
                                               unsigned short* __restrict__ sact16,
                                               unsigned long long* __restrict__ tab,
                                               u32x4* __restrict__ A1pre,
                                               u32x4* __restrict__ A2pre,
                                               unsigned* __restrict__ slotk) {
    __shared__ short sWh[32][264];
    __shared__ short sWl[32][264];

    const int blk = blockIdx.x;
    const int c   = threadIdx.x;

    if (blk >= 512) {
        if (blk < 1536) {
            // ---- hash insert (winner = max edge id per key), direct CAS
            const int k = (blk - 512) * 256 + c;
            const unsigned j = (unsigned)eidx[k];
            const unsigned i = (unsigned)eidx[E_EDGES + k];
            const unsigned key = (j << 12) | i;
            const unsigned long long mine =
                ((unsigned long long)(key + 1u) << 18) | (unsigned)k;
            unsigned h = hashh(key);
            while (true) {
                const unsigned long long old = atomicCAS(&tab[h], 0ULL, mine);
                if (old == 0ULL) break;                     // claimed empty slot
                if ((unsigned)(old >> 18) == key + 1u) {    // key already present
                    atomicMax(&tab[h], mine);
                    break;
                }
                h = (h + 1u) & TMASK;
            }
            slotk[k] = h;          // unique, stable slot for this key
            return;
        } else {
            // ---- prepack: A1 = {Wb pair x2, pk(bb,0), 0}; A2 = {Wbs pair x2, 0, 0}
#pragma unroll
            for (int ee = 0; ee < 4; ++ee) {
                const int idx  = c + 256 * ee;
                const int g    = idx >> 6;
                const int lane = idx & 63;
                const int mm   = lane & 15;
                const int qq   = lane >> 4;

                const float4 w = *(const float4*)(Wb + (16 * g + mm) * EDGE_DIM + 4 * qq);
                u32x4 r1;
                r1.x = pack_bf16x2(w.x, w.y);
                r1.y = pack_bf16x2(w.z, w.w);
                r1.z = pack_bf16x2(bb[16 * g + mm], 0.0f);
                r1.w = 0u;
                A1pre[idx] = r1;

                u32x4 r2;
                if (mm < NBT) {
                    const float4 ws = *(const float4*)(Wbs + mm * IN_DIM + 16 * g + 4 * qq);
                    r2.x = pack_bf16x2(ws.x, ws.y);
                    r2.y = pack_bf16x2(ws.z, ws.w);
                } else {
                    r2.x = 0u; r2.y = 0u;
                }
                r2.z = 0u; r2.w = 0u;
                A2pre[idx] = r2;
            }
            return;
        }
    }

    // ---- GEMM1: block (rg, cg) = rows rg*64..+63, cols cg*32..+31 (R11)
    const int rg = blk >> 3;
    const int cg = blk & 7;

    {
        const int r  = c >> 3;
        const int cq = c & 7;
        const float* wrow = Wsh + (size_t)(cg * 32 + r) * IN_DIM;
#pragma unroll
        for (int k = 0; k < 4; ++k) {
            const int ch = cq + 8 * k;
            const float4 b0 = *(const float4*)(wrow + ch * 8);
            const float4 b1 = *(const float4*)(wrow + ch * 8 + 4);
            bf16x8 Bh, Bl;
            split_bf16(b0, b1, &Bh, &Bl);
            *(bf16x8*)&sWh[r][ch * 8] = Bh;
            *(bf16x8*)&sWl[r][ch * 8] = Bl;
        }
    }
    __syncthreads();

    const int lane = c & 63;
    const int wv   = c >> 6;
    const int m    = lane & 15;
    const int q    = lane >> 4;
    const int row0 = rg * 64 + wv * 16;

    f32x4v acc0, acc1;
    {
        const float b0 = bsh[cg * 32 + m];
        const float b1 = bsh[cg * 32 + 16 + m];
        acc0[0] = b0; acc0[1] = b0; acc0[2] = b0; acc0[3] = b0;
        acc1[0] = b1; acc1[1] = b1; acc1[2] = b1; acc1[3] = b1;
    }

    const float* ap = s + (size_t)(row0 + m) * IN_DIM + 8 * q;

#pragma unroll
    for (int c8 = 0; c8 < 8; ++c8) {
        const float4 a0 = *(const float4*)(ap + 32 * c8);
        const float4 a1 = *(const float4*)(ap + 32 * c8 + 4);
        bf16x8 Ah, Al;
        split_bf16(a0, a1, &Ah, &Al);

        {
            const bf16x8 Bh = *(const bf16x8*)&sWh[m][32 * c8 + 8 * q];
            const bf16x8 Bl = *(const bf16x8*)&sWl[m][32 * c8 + 8 * q];
            acc0 = __builtin_amdgcn_mfma_f32_16x16x32_bf16(Ah, Bh, acc0, 0, 0, 0);
            acc0 = __builtin_amdgcn_mfma_f32_16x16x32_bf16(Al, Bh, acc0, 0, 0, 0);
            acc0 = __builtin_amdgcn_mfma_f32_16x16x32_bf16(Ah, Bl, acc0, 0, 0, 0);
        }
        {
            const bf16x8 Bh = *(const bf16x8*)&sWh[16 + m][32 * c8 + 8 * q];
            const bf16x8 Bl = *(const bf16x8*)&sWl[16 + m][32 * c8 + 8 * q];
            acc1 = __builtin_amdgcn_mfma_f32_16x16x32_bf16(Ah, Bh, acc1, 0, 0, 0);
            acc1 = __builtin_amdgcn_mfma_f32_16x16x32_bf16(Al, Bh, acc1, 0, 0, 0);
            acc1 = __builtin_amdgcn_mfma_f32_16x16x32_bf16(Ah, Bl, acc1, 0, 0, 0);
        }
    }

#pragma unroll
    for (int r = 0; r < 4; ++r) {
        const int row = row0 + 4 * q + r;
        const float v0 = silu_f(acc0[r]);
        const float v1 = silu_f(acc1[r]);
        sact16[(size_t)row * IN_DIM + cg * 32 + m] =
            (unsigned short)(pack_bf16x2(v0, 0.0f) & 0xFFFFu);
        sact16[(size_t)row * IN_DIM + cg * 32 + 16 + m] =
            (unsigned short)(pack_bf16x2(v1, 0.0f) & 0xFFFFu);
    }
}

// fence helpers. Counted-wait safety rule (validated R4/R5/R8/R9):
// vmcnt(N) targeting cluster X requires N <= #STATICALLY-issued loads younger
// than X not yet provably retired. Dynamic loads (hash slow path) and older
// stores are legal anywhere but NEVER counted -> FIFO only makes waits stricter.
#define SB0()    __builtin_amdgcn_sched_barrier(0)
#define LGKM0()  do { __asm__ __volatile__("s_waitcnt lgkmcnt(0)" ::: "memory"); SB0(); } while (0)
#define VMW(n)   do { __asm__ __volatile__("s_waitcnt vmcnt(" #n ")" ::: "memory"); SB0(); } while (0)

// ---------------------------------------------------------------------------
// k_edges_mfma (R12): issue-count reduction on the R9 schedule.
//   blocks 0..575   : GEMM2 (moved FIRST for tail smoothing)
//   blocks 576..4671: edge tiles, 1 tile/wave, eighth-staged depth-3 pipeline.
//     NEW vs R9:
//     - si+sj injected via chained identity-MFMAs (P0 = I*SI; P0 = I*SJ + P0;
//       P = A1*B1 + P0): removes 16 bf16-unpacks + 4 adds per 2-MFMA group.
//     - one ds_read_b128/operand (32 distinct 16B chunks tile 512B ->
//       conflict-free; replaces 4-way-conflicted b64 pairs).
//     - forward lookup is DIRECT: tab[slotk[k]] (no probing; slot is unique &
//       stable). Reverse keeps 2-slot speculative resolve.
// ---------------------------------------------------------------------------
__global__ __launch_bounds__(256, 6) void k_edges_mfma(const int* __restrict__ eidx,
                                                       const float* __restrict__ e,
                                                       const unsigned long long* __restrict__ tab,
                                                       const unsigned short* __restrict__ sact16,
                                                       const u32x4* __restrict__ A1pre,
                                                       const u32x4* __restrict__ A2pre,
                                                       const float* __restrict__ bbs,
                                                       const float* __restrict__ Wa,
                                                       const float* __restrict__ ba,
                                                       const unsigned* __restrict__ slotk,
                                                       float* __restrict__ out) {
    __shared__ unsigned lds_all[4][1536];   // 6 KB/wave -> 24 KB/block
    const int blk  = blockIdx.x;
    const int lane = threadIdx.x & 63;
    const int wv   = threadIdx.x >> 6;
    const int m    = lane & 15;
    const int q    = lane >> 4;

    if (blk < 576) {
        // ---- GEMM2: wave -> (row_tile, col_tile) over 256 x 9 tiles
        const int wave = blk * 4 + wv;            // 0..2303
        const int rt = wave / 9;
        const int ct = wave - rt * 9;
        const int row0  = rt * 16;
        const int n_abs = ct * 16 + m;            // 0..143

        f32x4v acc;
        {
            const float bias = ba[n_abs];
            acc[0] = bias; acc[1] = bias; acc[2] = bias; acc[3] = bias;
        }

        const unsigned short* apu = sact16 + (size_t)(row0 + m) * IN_DIM + 8 * q;
        const float*          bp  = Wa + (size_t)n_abs * IN_DIM + 8 * q;

#pragma unroll
        for (int c8 = 0; c8 < 8; ++c8) {
            const bf16x8 A = *(const bf16x8*)(apu + 32 * c8);
            const float4 b0 = *(const float4*)(bp + 32 * c8);
            const float4 b1 = *(const float4*)(bp + 32 * c8 + 4);
            bf16x8 Bh, Bl;
            split_bf16(b0, b1, &Bh, &Bl);
            acc = __builtin_amdgcn_mfma_f32_16x16x32_bf16(A, Bh, acc, 0, 0, 0);
            acc = __builtin_amdgcn_mfma_f32_16x16x32_bf16(A, Bl, acc, 0, 0, 0);
        }
#pragma unroll
        for (int r = 0; r < 4; ++r) {
            const int row = row0 + 4 * q + r;
            if (n_abs < NAF)
                out[ATOMS_OFF + (size_t)row * NAF + n_abs] = acc[r];
            else
                out[LATENT_OFF + (size_t)row * LATENT + (n_abs - NAF)] = acc[r];
        }
        return;
    }

    // ---- edge tile: 1 tile (16 edges) per wave
    const int k0 = __builtin_amdgcn_readfirstlane(((blk - 576) * 4 + wv) * 16);
    unsigned* myl = lds_all[wv];
    const short one_q0 = (q == 0) ? (short)0x3F80 : (short)0;  // bf16(1.0)

    f32x4v acc_init;
#pragma unroll
    for (int r = 0; r < 4; ++r) {
        const int bond = 4 * q + r;
        acc_init[r] = (bond < NBT) ? bbs[bond] : 0.0f;
    }

    // identity A-fragment for the si/sj injection MFMAs: A[R][8+R] = 1.0
    // lane (m,q): one-hot bf16(1.0) at element m&7 iff q == 1 + (m>>3).
    // Built with compile-time union indices only (rule #20: no runtime idx).
    union { bf16x8 v; unsigned u[4]; } IA;
    {
        const int active = (q == 1 + (m >> 3));
        const unsigned val = active ? (0x3F80u << (16 * (m & 1))) : 0u;
        const int widx = (m & 7) >> 1;            // 0..3
        IA.u[0] = (widx == 0) ? val : 0u;
        IA.u[1] = (widx == 1) ? val : 0u;
        IA.u[2] = (widx == 2) ? val : 0u;
        IA.u[3] = (widx == 3) ? val : 0u;
    }
    const f32x4v zeroC = {0.0f, 0.0f, 0.0f, 0.0f};
    // per-lane byte offset of this lane's 16B si/sj sub-chunk within a group
    const int soff = 256 * (q >> 1) + 16 * m;

    // -------- front: indices, DIRECT forward slot, reverse spec probes ------
    const unsigned j_m = (unsigned)eidx[k0 + m];
    const unsigned i_m = (unsigned)eidx[E_EDGES + k0 + m];

    const char* si_base = (const char*)(sact16 + (size_t)i_m * IN_DIM);  // 512 B rows
    const char* sj_base = (const char*)(sact16 + (size_t)j_m * IN_DIM);

    const unsigned sl = slotk[k0 + m];                   // coalesced
    const unsigned long long fv = tab[sl];               // final winner record
    const unsigned keyR = (i_m << 12) | j_m;
    const unsigned hR = hashh(keyR);
    const unsigned long long sR0 = tab[hR];
    const unsigned long long sR1 = tab[(hR + 1u) & TMASK];

    // eighth staging (SB0-pinned, 2 static ops)
    auto stage_e = [&](int p, int qb) {
        gld_lds16(si_base + p * 64 + q * 16, (char*)myl + qb);
        gld_lds16(sj_base + p * 64 + q * 16, (char*)myl + qb + 1024);
        SB0();
    };

    stage_e(0, 0);        // E0 -> buf0
    stage_e(1, 2048);     // E1 -> buf1
    stage_e(2, 4096);     // E2 -> buf2

    // -------- resolve (overlapped with staging flight) --------
    const int wf = (int)(fv & 0x3FFFFu);                 // direct, no probe
    const int wr = resolve2(tab, keyR, sR0, sR1, hR);

    const float rsc = (wr >= 0) ? 0.5f : 0.0f;
    const int   wrc = (wr >= 0) ? wr : 0;
    const f32x4 ef = *(const f32x4*)(e + (size_t)wf  * EDGE_DIM + 4 * q);
    const f32x4 er = *(const f32x4*)(e + (size_t)wrc * EDGE_DIM + 4 * q);

    union { bf16x8 v; short s[8]; unsigned u[4]; } B1;
    {
        const f32x4 es = ef * 0.5f + er * rsc;
        B1.u[0] = pack_bf16x2(es[0], es[1]);
        B1.u[1] = pack_bf16x2(es[2], es[3]);
        B1.s[4] = one_q0; B1.s[5] = 0;
        B1.u[3] = 0u;
    }

    f32x4v acc0 = acc_init;
    f32x4v acc1 = {0.0f, 0.0f, 0.0f, 0.0f};

    // 2-group compute on one eighth-buffer at BYTE base qbB (gbase = 2p):
    // group g (half = g&1): lane reads its 16B si chunk at
    // qbB + 512*half + soff (32 distinct chunks tile 512B -> conflict-free);
    // sj at +1024. si/sj enter the MFMA chain raw (no unpack):
    //   P0 = I*SI ; P0 = I*SJ + P0 ; P = A1*B1 + P0.
    auto qcompute2 = [&](int qbB, int gbase) {
#pragma unroll
        for (int gp = 0; gp < 2; ++gp) {
            const int g    = gbase + gp;
            const int half = g & 1;

            const bf16x8 SI = *(const bf16x8*)((const char*)myl + qbB + 512 * half + soff);
            const bf16x8 SJ = *(const bf16x8*)((const char*)myl + qbB + 512 * half + 1024 + soff);

            const u32x4 r1 = A1pre[g * 64 + lane];
            const u32x4 r2 = A2pre[g * 64 + lane];
            union { bf16x8 v; unsigned u[4]; } A1, A2;
            A1.u[0] = r1.x; A1.u[1] = r1.y; A1.u[2] = r1.z; A1.u[3] = 0u;
            A2.u[0] = r2.x; A2.u[1] = r2.y; A2.u[2] = 0u;   A2.u[3] = 0u;

            f32x4v P0 = __builtin_amdgcn_mfma_f32_16x16x32_bf16(IA.v, SI, zeroC, 0, 0, 0);
            P0 = __builtin_amdgcn_mfma_f32_16x16x32_bf16(IA.v, SJ, P0, 0, 0, 0);
            const f32x4v P = __builtin_amdgcn_mfma_f32_16x16x32_bf16(A1.v, B1.v, P0, 0, 0, 0);

            union { bf16x8 v; unsigned u[4]; } B2;
            B2.u[0] = pack_bf16x2(silu_f(P[0]), silu_f(P[1]));
            B2.u[1] = pack_bf16x2(silu_f(P[2]), silu_f(P[3]));
            B2.u[2] = 0u; B2.u[3] = 0u;

            if (gp & 1) acc1 = __builtin_amdgcn_mfma_f32_16x16x32_bf16(A2.v, B2.v, acc1, 0, 0, 0);
            else        acc0 = __builtin_amdgcn_mfma_f32_16x16x32_bf16(A2.v, B2.v, acc0, 0, 0, 0);
        }
    };

    // -------- 8-phase depth-3 counted-vmcnt pipeline (R9 schedule) --------
    // B1's compiler wait on ef/er (youngest loads) drains E0-E2 (FIFO);
    // explicit VMW(0) is the async-LDS fence (rule 21), timing-free here.
    VMW(0);
    qcompute2(0, 0);        // E0 @ buf0
    LGKM0(); stage_e(3, 0);        // E3 -> buf0

    VMW(2);                 // free: E1 already drained; <= {E3} outstanding
    qcompute2(2048, 2);     // E1 @ buf1
    LGKM0(); stage_e(4, 2048);     // E4 -> buf1

    VMW(4);                 // free: E2 drained; <= {E3,E4} outstanding
    qcompute2(4096, 4);     // E2 @ buf2
    LGKM0(); stage_e(5, 4096);     // E5 -> buf2

    VMW(4);                 // E3 done (younger static: E4,E5 = 4)
    qcompute2(0, 6);        // E3 @ buf0
    LGKM0(); stage_e(6, 0);        // E6 -> buf0

    VMW(4);                 // E4 done (younger static: E5,E6 = 4)
    qcompute2(2048, 8);     // E4 @ buf1
    LGKM0(); stage_e(7, 2048);     // E7 -> buf1

    VMW(4);                 // E5 done (younger static: E6,E7 = 4)
    qcompute2(4096, 10);    // E5 @ buf2

    VMW(2);                 // E6 done (younger static: E7 = 2)
    qcompute2(0, 12);       // E6 @ buf0

    VMW(0);                 // E7 done
    qcompute2(2048, 14);    // E7 @ buf1

    // -------- store bonds (plain stores; WRITE_SIZE 7.5 MB since R9) -------
    const f32x4v accT = acc0 + acc1;
    float* op = out + BONDS_OFF + (size_t)(k0 + m) * NBT;
    if (q == 0) {
        op[0] = accT[0];
        op[1] = accT[1];
        op[2] = accT[2];
        op[3] = accT[3];
    } else if (q == 1) {
        op[4] = accT[0];
    }
}

// ---------------------------------------------------------------------------
extern "C" void kernel_launch(void* const* d_in, const int* in_sizes, int n_in,
                              void* d_out, int out_size, void* d_ws, size_t ws_size,
                              hipStream_t stream) {
    const float* s   = (const float*)d_in[0];
    const float* e   = (const float*)d_in[1];
    const int*   eix = (const int*)d_in[3];
    const float* Wsh = (const float*)d_in[4];
    const float* bsh = (const float*)d_in[5];
    const float* Wb  = (const float*)d_in[6];
    const float* bbo = (const float*)d_in[7];
    const float* Wbs = (const float*)d_in[8];
    const float* bbs = (const float*)d_in[9];
    const float* Wa  = (const float*)d_in[10];
    const float* ba  = (const float*)d_in[11];
    float* out = (float*)d_out;

    char* ws = (char*)d_ws;
    unsigned short*     sact16 = (unsigned short*)ws;             // 2 MB @ 0
    u32x4*              A1pre  = (u32x4*)(ws + (2u << 20));       // 16 KB
    u32x4*              A2pre  = (u32x4*)(ws + (2u << 20) + 16384);
    unsigned long long* tab    = (unsigned long long*)(ws + (3u << 20)); // 8 MB @ 3..11 MB
    unsigned*           slotk  = (unsigned*)(ws + (11u << 20));   // 1 MB @ 11 MB

    (void)hipMemsetAsync(tab, 0x00, TSIZE * sizeof(unsigned long long), stream);

    k_front<<<1537, 256, 0, stream>>>(s, Wsh, bsh, eix, Wb, bbo, Wbs,
                                      sact16, tab, A1pre, A2pre, slotk);
    k_edges_mfma<<<4672, 256, 0, stream>>>(eix, e, tab, sact16,
                                           A1pre, A2pre, bbs, Wa, ba, slotk, out);
}